// Round 3
// baseline (4864.702 us; speedup 1.0000x reference)
//
#include <hip/hip_runtime.h>

#define B_   128
#define T_   16

typedef __bf16 bf16;
typedef __bf16 bf16x8 __attribute__((ext_vector_type(8)));
typedef float f32x4 __attribute__((ext_vector_type(4)));

#define GLL(SRC, DST) __builtin_amdgcn_global_load_lds( \
    (const __attribute__((address_space(1))) void*)(SRC), \
    (__attribute__((address_space(3))) void*)(DST), 16, 0, 0)

__device__ __forceinline__ float sigf(float x) { return 1.f / (1.f + expf(-x)); }

// ---------------------------------------------------------------------------
// Fused split-K GEMM + epilogue. C = A[128 x K] @ W[N x K]^T.
// Tile 128(M) x 128(N), BK=64, 4 waves each 64x64. Partials per z-chunk;
// last block per n-tile (atomic counter) sums slices in fixed z order and
// applies epilogue EP:
//  0: base = sum + b1[n]+b2[n]                  (gate-permuted cols)
//  1: enc LSTM: gates = sum + base -> c_enc, h_enc -> aew[5120+j]
//  2: mu/sig interleaved -> z -> adw[0..256)
//  3: dec LSTM: gates = sum + b1 + b2 -> c_dec, h -> aew[4096+j], adw[256+j]
//  4: c_t += sum + b1[n]; aew[n] = -sig(c); outp = sig(c)
// ---------------------------------------------------------------------------
template<int EP>
__global__ __launch_bounds__(256) void gemm_ep(
    const bf16* __restrict__ A, int lda,
    const bf16* __restrict__ W, int ldw, int Kc,
    float* __restrict__ part, int* __restrict__ cnt,
    const float* __restrict__ base,
    float* __restrict__ cst,
    bf16* __restrict__ aew, bf16* __restrict__ adw,
    const float* __restrict__ b1, const float* __restrict__ b2,
    const float* __restrict__ eps_t, float* __restrict__ outp)
{
    __shared__ bf16 As[2][128 * 64];
    __shared__ bf16 Bs[2][128 * 64];
    __shared__ int s_last;

    const int nt = blockIdx.x, zz = blockIdx.y;
    const int tid = threadIdx.x, lane = tid & 63, wave = tid >> 6;
    const bf16* Ab = A + (size_t)zz * Kc;
    const bf16* Wb = W + (size_t)nt * 128 * ldw + (size_t)zz * Kc;

    const int srow = lane >> 3;                       // 0..7
    const int scol = ((lane & 7) ^ srow) << 3;        // pre-swizzled src col (elems)

    f32x4 acc[4][4];
#pragma unroll
    for (int m = 0; m < 4; ++m)
#pragma unroll
        for (int n = 0; n < 4; ++n) acc[m][n] = (f32x4){0.f, 0.f, 0.f, 0.f};

    auto stage = [&](int bq, int koff) {
#pragma unroll
        for (int i = 0; i < 4; ++i) {
            int rb = i * 32 + wave * 8;
            GLL(Ab + (size_t)(rb + srow) * lda + koff + scol, &As[bq][rb * 64]);
        }
#pragma unroll
        for (int i = 0; i < 4; ++i) {
            int rb = i * 32 + wave * 8;
            GLL(Wb + (size_t)(rb + srow) * ldw + koff + scol, &Bs[bq][rb * 64]);
        }
    };

    const int nk = Kc >> 6;
    stage(0, 0);
    int bq = 0;

    const int wm = wave & 1, wn = wave >> 1;
    const int ln = lane & 15;
    const int rA = wm * 64 + ln;
    const int rB = wn * 64 + ln;
    const int swz = (lane & 7) << 4;
    const int kq  = (lane >> 4) << 4;

    for (int it = 0; it < nk; ++it) {
        __syncthreads();
        if (it + 1 < nk) stage(bq ^ 1, (it + 1) << 6);
        const bf16* as = As[bq];
        const bf16* bs = Bs[bq];
#pragma unroll
        for (int k2 = 0; k2 < 2; ++k2) {
            const int co = (((k2 << 6) | kq) ^ swz) >> 1;
            bf16x8 a[4], b[4];
#pragma unroll
            for (int f = 0; f < 4; ++f) a[f] = *(const bf16x8*)&as[(rA + f * 16) * 64 + co];
#pragma unroll
            for (int f = 0; f < 4; ++f) b[f] = *(const bf16x8*)&bs[(rB + f * 16) * 64 + co];
#pragma unroll
            for (int m = 0; m < 4; ++m)
#pragma unroll
                for (int n = 0; n < 4; ++n)
                    acc[m][n] = __builtin_amdgcn_mfma_f32_16x16x32_bf16(a[m], b[n], acc[m][n], 0, 0, 0);
        }
        bq ^= 1;
    }

    // partial store
    float* myp = part + ((size_t)(zz * gridDim.x + nt)) * (128 * 128);
    const int q = lane >> 4;
#pragma unroll
    for (int m = 0; m < 4; ++m) {
        int row = wm * 64 + m * 16 + q * 4;
#pragma unroll
        for (int n = 0; n < 4; ++n) {
            int col = wn * 64 + n * 16 + ln;
#pragma unroll
            for (int r = 0; r < 4; ++r)
                myp[(size_t)(row + r) * 128 + col] = acc[m][n][r];
        }
    }

    __threadfence();
    __syncthreads();
    if (tid == 0) {
        int old = atomicAdd(&cnt[nt], 1);
        s_last = (old == (int)gridDim.y - 1);
    }
    __syncthreads();
    if (!s_last) return;
    __threadfence();

    // ---- epilogue by last block ----
    const int Zn = gridDim.y;
    const size_t sl = (size_t)gridDim.x * (128 * 128);
    const float* p0 = part + (size_t)nt * (128 * 128);

    for (int itm = tid; itm < 128 * 32; itm += 256) {
        const int row = itm >> 5, cq = itm & 31;
        const int c0 = cq << 2;
        float s0 = 0.f, s1 = 0.f, s2 = 0.f, s3 = 0.f;
        for (int z = 0; z < Zn; ++z) {
            const float* p = p0 + (size_t)z * sl + (size_t)row * 128 + c0;
            s0 += p[0]; s1 += p[1]; s2 += p[2]; s3 += p[3];
        }
        if (EP == 0) {
            int j = nt * 32 + cq;
            int nb = row * 4096 + nt * 128 + c0;
            cst[nb + 0] = s0 + b1[j]        + b2[j];
            cst[nb + 1] = s1 + b1[1024 + j] + b2[1024 + j];
            cst[nb + 2] = s2 + b1[2048 + j] + b2[2048 + j];
            cst[nb + 3] = s3 + b1[3072 + j] + b2[3072 + j];
        } else if (EP == 1) {
            int j = nt * 32 + cq;
            const float* bb = base + (size_t)row * 4096 + nt * 128 + c0;
            float gi = s0 + bb[0], gf = s1 + bb[1], gg = s2 + bb[2], go = s3 + bb[3];
            int ci = row * 1024 + j;
            float cn = sigf(gf) * cst[ci] + sigf(gi) * tanhf(gg);
            cst[ci] = cn;
            aew[(size_t)row * 6144 + 5120 + j] = (bf16)(sigf(go) * tanhf(cn));
        } else if (EP == 2) {
            int zi = nt * 64 + cq * 2;
            float z0 = eps_t[row * 256 + zi]     * expf(s1 + b2[zi])     + (s0 + b1[zi]);
            float z1 = eps_t[row * 256 + zi + 1] * expf(s3 + b2[zi + 1]) + (s2 + b1[zi + 1]);
            adw[(size_t)row * 1280 + zi]     = (bf16)z0;
            adw[(size_t)row * 1280 + zi + 1] = (bf16)z1;
        } else if (EP == 3) {
            int j = nt * 32 + cq;
            float gi = s0 + b1[j]        + b2[j];
            float gf = s1 + b1[1024 + j] + b2[1024 + j];
            float gg = s2 + b1[2048 + j] + b2[2048 + j];
            float go = s3 + b1[3072 + j] + b2[3072 + j];
            int ci = row * 1024 + j;
            float cn = sigf(gf) * cst[ci] + sigf(gi) * tanhf(gg);
            cst[ci] = cn;
            float h = sigf(go) * tanhf(cn);
            aew[(size_t)row * 6144 + 4096 + j] = (bf16)h;
            adw[(size_t)row * 1280 + 256 + j]  = (bf16)h;
        } else if (EP == 4) {
            int n0 = nt * 128 + c0;
            int ci = row * 4096 + n0;
            float sg[4] = {s0, s1, s2, s3};
#pragma unroll
            for (int g = 0; g < 4; ++g) {
                float cv = cst[ci + g] + sg[g] + b1[n0 + g];
                cst[ci + g] = cv;
                float sv = sigf(cv);
                aew[(size_t)row * 6144 + n0 + g] = (bf16)(-sv);
                outp[ci + g] = sv;
            }
        }
    }
}

// ---------------- init + weight packing ----------------
#define PBL (B_ * 4096)
#define PBH (B_ * 1024)

__global__ void init_k(const float* __restrict__ x, const float* __restrict__ c0,
                       const float* __restrict__ h0e, const float* __restrict__ h0d,
                       float* __restrict__ c_t, float* __restrict__ c_enc,
                       float* __restrict__ c_dec, bf16* __restrict__ ae0,
                       bf16* __restrict__ ad0, bf16* __restrict__ x_bf,
                       int* __restrict__ cnt) {
    int i = blockIdx.x * 256 + threadIdx.x;
    if (i >= PBL) return;
    int b = i >> 12, n = i & 4095;
    float c = c0[n];
    c_t[i] = c;
    ae0[(size_t)b * 6144 + n] = (bf16)(-sigf(c));
    x_bf[i] = (bf16)x[i];
    if (i < PBH) {
        int b2 = i >> 10, j = i & 1023;
        c_enc[i] = 0.f;
        c_dec[i] = 0.f;
        bf16 hd = (bf16)h0d[j], he = (bf16)h0e[j];
        ae0[(size_t)b2 * 6144 + 4096 + j] = hd;
        ae0[(size_t)b2 * 6144 + 5120 + j] = he;
        ad0[(size_t)b2 * 1280 + 256 + j]  = hd;
    }
    if (i < 65 * 32) cnt[i] = 0;
}

__device__ __forceinline__ bf16x8 cvt8(const float* s) {
    float4 a = *(const float4*)s, b = *(const float4*)(s + 4);
    bf16x8 v = { (bf16)a.x, (bf16)a.y, (bf16)a.z, (bf16)a.w,
                 (bf16)b.x, (bf16)b.y, (bf16)b.z, (bf16)b.w };
    return v;
}

// Wenc'[n'][0..6144): n' = 4j+g <-> n = g*1024+j; cols: xhat(4096)|hdec(1024)|henc(1024)
__global__ void conv_enc_k(const float* __restrict__ Wih, const float* __restrict__ Whh,
                           bf16* __restrict__ dst) {
    int id = blockIdx.x * 256 + threadIdx.x;
    if (id >= 4096 * 768) return;
    int np = id / 768, c = (id - np * 768) * 8;
    int n = ((np & 3) << 10) + (np >> 2);
    const float* src = (c < 4096) ? Wih + (size_t)n * 9216 + 4096 + c
                     : (c < 5120) ? Wih + (size_t)n * 9216 + 8192 + (c - 4096)
                                  : Whh + (size_t)n * 1024 + (c - 5120);
    *(bf16x8*)(dst + (size_t)np * 6144 + c) = cvt8(src);
}

__global__ void conv_sum_k(const float* __restrict__ Wih, bf16* __restrict__ dst) {
    int id = blockIdx.x * 256 + threadIdx.x;
    if (id >= 4096 * 512) return;
    int np = id >> 9, c = (id & 511) * 8;
    int n = ((np & 3) << 10) + (np >> 2);
    const float* s1 = Wih + (size_t)n * 9216 + c;
    const float* s2 = s1 + 4096;
    float4 a = *(const float4*)s1, b = *(const float4*)(s1 + 4);
    float4 e = *(const float4*)s2, f = *(const float4*)(s2 + 4);
    bf16x8 v = { (bf16)(a.x + e.x), (bf16)(a.y + e.y), (bf16)(a.z + e.z), (bf16)(a.w + e.w),
                 (bf16)(b.x + f.x), (bf16)(b.y + f.y), (bf16)(b.z + f.z), (bf16)(b.w + f.w) };
    *(bf16x8*)(dst + (size_t)np * 4096 + c) = v;
}

__global__ void conv_dec_k(const float* __restrict__ Wih, const float* __restrict__ Whh,
                           bf16* __restrict__ dst) {
    int id = blockIdx.x * 256 + threadIdx.x;
    if (id >= 4096 * 160) return;
    int np = id / 160, c = (id - np * 160) * 8;
    int n = ((np & 3) << 10) + (np >> 2);
    const float* src = (c < 256) ? Wih + (size_t)n * 256 + c
                                 : Whh + (size_t)n * 1024 + (c - 256);
    *(bf16x8*)(dst + (size_t)np * 1280 + c) = cvt8(src);
}

// Wms'[n'][k]: n' = 2*zi + s, s=0 -> Wmu[zi], s=1 -> Wsig[zi]
__global__ void conv_ms_k(const float* __restrict__ Wmu, const float* __restrict__ Wsig,
                          bf16* __restrict__ dst) {
    int id = blockIdx.x * 256 + threadIdx.x;
    if (id >= 512 * 128) return;
    int np = id >> 7, c = (id & 127) * 8;
    int zi = np >> 1;
    const float* src = ((np & 1) ? Wsig : Wmu) + (size_t)zi * 1024 + c;
    *(bf16x8*)(dst + (size_t)np * 1024 + c) = cvt8(src);
}

__global__ void conv_wr_k(const float* __restrict__ Wwr, bf16* __restrict__ dst) {
    int id = blockIdx.x * 256 + threadIdx.x;
    if (id >= 4096 * 128) return;
    *(bf16x8*)(dst + (size_t)id * 8) = cvt8(Wwr + (size_t)id * 8);
}

// ---------------- launch ----------------
extern "C" void kernel_launch(void* const* d_in, const int* in_sizes, int n_in,
                              void* d_out, int out_size, void* d_ws, size_t ws_size,
                              hipStream_t stream) {
    const float* x      = (const float*)d_in[0];
    const float* eps    = (const float*)d_in[1];
    const float* c0     = (const float*)d_in[2];
    const float* h0e    = (const float*)d_in[3];
    const float* h0d    = (const float*)d_in[4];
    const float* W_ih_e = (const float*)d_in[5];
    const float* b_ih_e = (const float*)d_in[6];
    const float* W_hh_e = (const float*)d_in[7];
    const float* b_hh_e = (const float*)d_in[8];
    const float* W_mu   = (const float*)d_in[9];
    const float* b_mu   = (const float*)d_in[10];
    const float* W_sig  = (const float*)d_in[11];
    const float* b_sig  = (const float*)d_in[12];
    const float* W_ih_d = (const float*)d_in[13];
    const float* b_ih_d = (const float*)d_in[14];
    const float* W_hh_d = (const float*)d_in[15];
    const float* b_hh_d = (const float*)d_in[16];
    const float* W_wr   = (const float*)d_in[17];
    const float* b_wr   = (const float*)d_in[18];
    float* out = (float*)d_out;

    float* f = (float*)d_ws;
    float* c_t   = f; f += 524288;
    float* base  = f; f += 524288;
    float* part  = f; f += (size_t)16 * 32 * 16384;   // 8.4M floats
    float* c_enc = f; f += 131072;
    float* c_dec = f; f += 131072;
    int*   cnt   = (int*)f; f += 2304;                // 65*32 counters (+pad)
    bf16* bp      = (bf16*)f;
    bf16* act_enc = bp; bp += (size_t)2 * B_ * 6144;
    bf16* act_dec = bp; bp += (size_t)2 * B_ * 1280;
    bf16* x_bf    = bp; bp += (size_t)B_ * 4096;
    bf16* Wenc    = bp; bp += (size_t)4096 * 6144;
    bf16* Wsum    = bp; bp += (size_t)4096 * 4096;
    bf16* Wdec    = bp; bp += (size_t)4096 * 1280;
    bf16* Wms     = bp; bp += (size_t)512 * 1024;
    bf16* Wwr     = bp; bp += (size_t)4096 * 1024;

    dim3 blk(256);

    init_k<<<(PBL + 255) / 256, blk, 0, stream>>>(x, c0, h0e, h0d, c_t, c_enc, c_dec,
                                                  act_enc, act_dec, x_bf, cnt);
    conv_enc_k<<<(4096 * 768 + 255) / 256, blk, 0, stream>>>(W_ih_e, W_hh_e, Wenc);
    conv_sum_k<<<(4096 * 512 + 255) / 256, blk, 0, stream>>>(W_ih_e, Wsum);
    conv_dec_k<<<(4096 * 160 + 255) / 256, blk, 0, stream>>>(W_ih_d, W_hh_d, Wdec);
    conv_ms_k<<<(512 * 128 + 255) / 256, blk, 0, stream>>>(W_mu, W_sig, Wms);
    conv_wr_k<<<(4096 * 128 + 255) / 256, blk, 0, stream>>>(W_wr, Wwr);

    // base = b_ih_e + b_hh_e + x @ Wsum^T   (gate-permuted columns)
    gemm_ep<0><<<dim3(32, 8), blk, 0, stream>>>(x_bf, 4096, Wsum, 4096, 512,
        part, cnt, nullptr, base, nullptr, nullptr, b_ih_e, b_hh_e, nullptr, nullptr);

    for (int t = 0; t < T_; ++t) {
        const bf16* aer = act_enc + (size_t)(t & 1) * (B_ * 6144);
        bf16*       aew = act_enc + (size_t)((t + 1) & 1) * (B_ * 6144);
        bf16*       adr = act_dec + (size_t)(t & 1) * (B_ * 1280);
        bf16*       adw = act_dec + (size_t)((t + 1) & 1) * (B_ * 1280);

        // encoder gates: [negs | h_dec | h_enc] @ Wenc^T, K=6144, z=16
        gemm_ep<1><<<dim3(32, 16), blk, 0, stream>>>(aer, 6144, Wenc, 6144, 384,
            part, cnt + (1 + 4 * t) * 32, base, c_enc, aew, nullptr,
            nullptr, nullptr, nullptr, nullptr);
        // mu/sigma: h_enc_t @ Wms^T, N=512, K=1024 -> z into adr[0..256)
        gemm_ep<2><<<dim3(4, 4), blk, 0, stream>>>(aew + 5120, 6144, Wms, 1024, 256,
            part, cnt + (2 + 4 * t) * 32, nullptr, nullptr, nullptr, adr,
            b_mu, b_sig, eps + (size_t)t * (B_ * 256), nullptr);
        // decoder gates: [z | h_dec] @ Wdec^T, K=1280, z=5
        gemm_ep<3><<<dim3(32, 5), blk, 0, stream>>>(adr, 1280, Wdec, 1280, 256,
            part, cnt + (3 + 4 * t) * 32, nullptr, c_dec, aew, adw,
            b_ih_d, b_hh_d, nullptr, nullptr);
        // write: c_t += h_dec_t @ Wwr^T + b_wr; negs + out
        gemm_ep<4><<<dim3(32, 4), blk, 0, stream>>>(adw + 256, 1280, Wwr, 1024, 256,
            part, cnt + (4 + 4 * t) * 32, nullptr, c_t, aew, nullptr,
            b_wr, nullptr, nullptr, out);
    }
}

// Round 4
// 1063.805 us; speedup vs baseline: 4.5729x; 4.5729x over previous
//
#include <hip/hip_runtime.h>

#define B_   128
#define T_   16

typedef __bf16 bf16;
typedef __bf16 bf16x8 __attribute__((ext_vector_type(8)));
typedef float f32x4 __attribute__((ext_vector_type(4)));

#define GLL(SRC, DST) __builtin_amdgcn_global_load_lds( \
    (const __attribute__((address_space(1))) void*)(SRC), \
    (__attribute__((address_space(3))) void*)(DST), 16, 0, 0)

__device__ __forceinline__ float sigf(float x) { return 1.f / (1.f + expf(-x)); }

// ---------------------------------------------------------------------------
// Split-K GEMM, partials only. part[zz][nt] = A[128 x Kc@zz] @ W[nt-tile x Kc@zz]^T
// Tile 128(M) x 128(N), BK=64, single-buffered LDS (32 KB), 4 waves x 64x64.
// grid = (ntiles, zslices). No atomics, no fences — fin kernels reduce.
// ---------------------------------------------------------------------------
__global__ __launch_bounds__(256) void gemm_k(
    const bf16* __restrict__ A, int lda,
    const bf16* __restrict__ W, int ldw, int Kc,
    float* __restrict__ part)
{
    __shared__ bf16 As[128 * 64];
    __shared__ bf16 Bs[128 * 64];

    const int nt = blockIdx.x, zz = blockIdx.y;
    const int tid = threadIdx.x, lane = tid & 63, wave = tid >> 6;
    const bf16* Ab = A + (size_t)zz * Kc;
    const bf16* Wb = W + (size_t)nt * 128 * ldw + (size_t)zz * Kc;

    const int srow = lane >> 3;                    // 0..7
    const int scol = ((lane & 7) ^ srow) << 3;     // pre-swizzled source col (elems)

    f32x4 acc[4][4];
#pragma unroll
    for (int m = 0; m < 4; ++m)
#pragma unroll
        for (int n = 0; n < 4; ++n) acc[m][n] = (f32x4){0.f, 0.f, 0.f, 0.f};

    const int wm = wave & 1, wn = wave >> 1;
    const int ln = lane & 15;
    const int rA = wm * 64 + ln;
    const int rB = wn * 64 + ln;
    const int swz = (lane & 7) << 4;
    const int kq  = (lane >> 4) << 4;

    const int nk = Kc >> 6;
    for (int it = 0; it < nk; ++it) {
        if (it) __syncthreads();                   // prev compute done before overwrite
        const int koff = it << 6;
#pragma unroll
        for (int i = 0; i < 4; ++i) {
            int rb = i * 32 + wave * 8;
            GLL(Ab + (size_t)(rb + srow) * lda + koff + scol, &As[rb * 64]);
        }
#pragma unroll
        for (int i = 0; i < 4; ++i) {
            int rb = i * 32 + wave * 8;
            GLL(Wb + (size_t)(rb + srow) * ldw + koff + scol, &Bs[rb * 64]);
        }
        __syncthreads();                           // vmcnt(0) drained by compiler
#pragma unroll
        for (int k2 = 0; k2 < 2; ++k2) {
            const int co = (((k2 << 6) | kq) ^ swz) >> 1;
            bf16x8 a[4], b[4];
#pragma unroll
            for (int f = 0; f < 4; ++f) a[f] = *(const bf16x8*)&As[(rA + f * 16) * 64 + co];
#pragma unroll
            for (int f = 0; f < 4; ++f) b[f] = *(const bf16x8*)&Bs[(rB + f * 16) * 64 + co];
#pragma unroll
            for (int m = 0; m < 4; ++m)
#pragma unroll
                for (int n = 0; n < 4; ++n)
                    acc[m][n] = __builtin_amdgcn_mfma_f32_16x16x32_bf16(a[m], b[n], acc[m][n], 0, 0, 0);
        }
    }

    float* myp = part + ((size_t)(zz * gridDim.x + nt)) * (128 * 128);
    const int q = lane >> 4;
#pragma unroll
    for (int m = 0; m < 4; ++m) {
        int row = wm * 64 + m * 16 + q * 4;
#pragma unroll
        for (int n = 0; n < 4; ++n) {
            int col = wn * 64 + n * 16 + ln;
#pragma unroll
            for (int r = 0; r < 4; ++r)
                myp[(size_t)(row + r) * 128 + col] = acc[m][n][r];
        }
    }
}

// ---------------------------------------------------------------------------
// fin: reduce ZN partial slices + epilogue EP. grid = (ntiles, 4 row-blocks).
//  0: base = sum + b1[n]+b2[n]                  (gate-permuted cols)
//  1: enc LSTM: gates = sum + base -> c_enc, h_enc -> aew[5120+j]
//  2: mu/sig interleaved -> z -> adw[0..256)
//  3: dec LSTM: gates = sum + b1 + b2 -> c_dec, h -> aew[4096+j], adw[256+j]
//  4: c_t += sum + b1[n]; aew[n] = -sig(c); if(outp) outp = sig(c)
// ---------------------------------------------------------------------------
template<int EP, int ZN>
__global__ __launch_bounds__(256) void fin_k(
    const float* __restrict__ part,
    const float* __restrict__ base,
    float* __restrict__ cst,
    bf16* __restrict__ aew, bf16* __restrict__ adw,
    const float* __restrict__ b1, const float* __restrict__ b2,
    const float* __restrict__ eps_t, float* __restrict__ outp)
{
    const int nt = blockIdx.x, rb = blockIdx.y;
    const int ntiles = gridDim.x;
    const size_t sl = (size_t)ntiles * (128 * 128);
    const float* p0 = part + (size_t)nt * (128 * 128);

#pragma unroll
    for (int it = 0; it < 4; ++it) {
        const int li  = it * 256 + threadIdx.x;       // 0..1023
        const int row = rb * 32 + (li >> 5);
        const int cq  = li & 31;
        const int c0  = cq << 2;

        float s0 = 0.f, s1 = 0.f, s2 = 0.f, s3 = 0.f;
#pragma unroll
        for (int z = 0; z < ZN; ++z) {
            float4 p = *(const float4*)(p0 + (size_t)z * sl + (size_t)row * 128 + c0);
            s0 += p.x; s1 += p.y; s2 += p.z; s3 += p.w;
        }

        if (EP == 0) {
            int j = nt * 32 + cq;
            int nb = row * 4096 + nt * 128 + c0;
            cst[nb + 0] = s0 + b1[j]        + b2[j];
            cst[nb + 1] = s1 + b1[1024 + j] + b2[1024 + j];
            cst[nb + 2] = s2 + b1[2048 + j] + b2[2048 + j];
            cst[nb + 3] = s3 + b1[3072 + j] + b2[3072 + j];
        } else if (EP == 1) {
            int j = nt * 32 + cq;
            float4 bb = *(const float4*)(base + (size_t)row * 4096 + nt * 128 + c0);
            float gi = s0 + bb.x, gf = s1 + bb.y, gg = s2 + bb.z, go = s3 + bb.w;
            int ci = row * 1024 + j;
            float cn = sigf(gf) * cst[ci] + sigf(gi) * tanhf(gg);
            cst[ci] = cn;
            aew[(size_t)row * 6144 + 5120 + j] = (bf16)(sigf(go) * tanhf(cn));
        } else if (EP == 2) {
            int zi = nt * 64 + cq * 2;
            float z0 = eps_t[row * 256 + zi]     * expf(s1 + b2[zi])     + (s0 + b1[zi]);
            float z1 = eps_t[row * 256 + zi + 1] * expf(s3 + b2[zi + 1]) + (s2 + b1[zi + 1]);
            adw[(size_t)row * 1280 + zi]     = (bf16)z0;
            adw[(size_t)row * 1280 + zi + 1] = (bf16)z1;
        } else if (EP == 3) {
            int j = nt * 32 + cq;
            float gi = s0 + b1[j]        + b2[j];
            float gf = s1 + b1[1024 + j] + b2[1024 + j];
            float gg = s2 + b1[2048 + j] + b2[2048 + j];
            float go = s3 + b1[3072 + j] + b2[3072 + j];
            int ci = row * 1024 + j;
            float cn = sigf(gf) * cst[ci] + sigf(gi) * tanhf(gg);
            cst[ci] = cn;
            float h = sigf(go) * tanhf(cn);
            aew[(size_t)row * 6144 + 4096 + j] = (bf16)h;
            adw[(size_t)row * 1280 + 256 + j]  = (bf16)h;
        } else if (EP == 4) {
            int n0 = nt * 128 + c0;
            int ci = row * 4096 + n0;
            float sg[4] = {s0, s1, s2, s3};
#pragma unroll
            for (int g = 0; g < 4; ++g) {
                float cv = cst[ci + g] + sg[g] + b1[n0 + g];
                cst[ci + g] = cv;
                float sv = sigf(cv);
                aew[(size_t)row * 6144 + n0 + g] = (bf16)(-sv);
                if (outp) outp[ci + g] = sv;
            }
        }
    }
}

// ---------------- init + weight packing ----------------
#define PBL (B_ * 4096)
#define PBH (B_ * 1024)

__global__ void init_k(const float* __restrict__ x, const float* __restrict__ c0,
                       const float* __restrict__ h0e, const float* __restrict__ h0d,
                       float* __restrict__ c_t, float* __restrict__ c_enc,
                       float* __restrict__ c_dec, bf16* __restrict__ ae,
                       bf16* __restrict__ ad, bf16* __restrict__ x_bf) {
    int i = blockIdx.x * 256 + threadIdx.x;
    if (i >= PBL) return;
    int b = i >> 12, n = i & 4095;
    float c = c0[n];
    c_t[i] = c;
    ae[(size_t)b * 6144 + n] = (bf16)(-sigf(c));
    x_bf[i] = (bf16)x[i];
    if (i < PBH) {
        int b2 = i >> 10, j = i & 1023;
        c_enc[i] = 0.f;
        c_dec[i] = 0.f;
        bf16 hd = (bf16)h0d[j], he = (bf16)h0e[j];
        ae[(size_t)b2 * 6144 + 4096 + j] = hd;
        ae[(size_t)b2 * 6144 + 5120 + j] = he;
        ad[(size_t)b2 * 1280 + 256 + j]  = hd;
    }
}

__device__ __forceinline__ bf16x8 cvt8(const float* s) {
    float4 a = *(const float4*)s, b = *(const float4*)(s + 4);
    bf16x8 v = { (bf16)a.x, (bf16)a.y, (bf16)a.z, (bf16)a.w,
                 (bf16)b.x, (bf16)b.y, (bf16)b.z, (bf16)b.w };
    return v;
}

// Wenc'[n'][0..6144): n' = 4j+g <-> n = g*1024+j; cols: xhat(4096)|hdec(1024)|henc(1024)
__global__ void conv_enc_k(const float* __restrict__ Wih, const float* __restrict__ Whh,
                           bf16* __restrict__ dst) {
    int id = blockIdx.x * 256 + threadIdx.x;
    if (id >= 4096 * 768) return;
    int np = id / 768, c = (id - np * 768) * 8;
    int n = ((np & 3) << 10) + (np >> 2);
    const float* src = (c < 4096) ? Wih + (size_t)n * 9216 + 4096 + c
                     : (c < 5120) ? Wih + (size_t)n * 9216 + 8192 + (c - 4096)
                                  : Whh + (size_t)n * 1024 + (c - 5120);
    *(bf16x8*)(dst + (size_t)np * 6144 + c) = cvt8(src);
}

__global__ void conv_sum_k(const float* __restrict__ Wih, bf16* __restrict__ dst) {
    int id = blockIdx.x * 256 + threadIdx.x;
    if (id >= 4096 * 512) return;
    int np = id >> 9, c = (id & 511) * 8;
    int n = ((np & 3) << 10) + (np >> 2);
    const float* s1 = Wih + (size_t)n * 9216 + c;
    const float* s2 = s1 + 4096;
    float4 a = *(const float4*)s1, b = *(const float4*)(s1 + 4);
    float4 e = *(const float4*)s2, f = *(const float4*)(s2 + 4);
    bf16x8 v = { (bf16)(a.x + e.x), (bf16)(a.y + e.y), (bf16)(a.z + e.z), (bf16)(a.w + e.w),
                 (bf16)(b.x + f.x), (bf16)(b.y + f.y), (bf16)(b.z + f.z), (bf16)(b.w + f.w) };
    *(bf16x8*)(dst + (size_t)np * 4096 + c) = v;
}

__global__ void conv_dec_k(const float* __restrict__ Wih, const float* __restrict__ Whh,
                           bf16* __restrict__ dst) {
    int id = blockIdx.x * 256 + threadIdx.x;
    if (id >= 4096 * 160) return;
    int np = id / 160, c = (id - np * 160) * 8;
    int n = ((np & 3) << 10) + (np >> 2);
    const float* src = (c < 256) ? Wih + (size_t)n * 256 + c
                                 : Whh + (size_t)n * 1024 + (c - 256);
    *(bf16x8*)(dst + (size_t)np * 1280 + c) = cvt8(src);
}

// Wms'[n'][k]: n' = 2*zi + s, s=0 -> Wmu[zi], s=1 -> Wsig[zi]
__global__ void conv_ms_k(const float* __restrict__ Wmu, const float* __restrict__ Wsig,
                          bf16* __restrict__ dst) {
    int id = blockIdx.x * 256 + threadIdx.x;
    if (id >= 512 * 128) return;
    int np = id >> 7, c = (id & 127) * 8;
    int zi = np >> 1;
    const float* src = ((np & 1) ? Wsig : Wmu) + (size_t)zi * 1024 + c;
    *(bf16x8*)(dst + (size_t)np * 1024 + c) = cvt8(src);
}

__global__ void conv_wr_k(const float* __restrict__ Wwr, bf16* __restrict__ dst) {
    int id = blockIdx.x * 256 + threadIdx.x;
    if (id >= 4096 * 128) return;
    *(bf16x8*)(dst + (size_t)id * 8) = cvt8(Wwr + (size_t)id * 8);
}

// ---------------- launch ----------------
extern "C" void kernel_launch(void* const* d_in, const int* in_sizes, int n_in,
                              void* d_out, int out_size, void* d_ws, size_t ws_size,
                              hipStream_t stream) {
    const float* x      = (const float*)d_in[0];
    const float* eps    = (const float*)d_in[1];
    const float* c0     = (const float*)d_in[2];
    const float* h0e    = (const float*)d_in[3];
    const float* h0d    = (const float*)d_in[4];
    const float* W_ih_e = (const float*)d_in[5];
    const float* b_ih_e = (const float*)d_in[6];
    const float* W_hh_e = (const float*)d_in[7];
    const float* b_hh_e = (const float*)d_in[8];
    const float* W_mu   = (const float*)d_in[9];
    const float* b_mu   = (const float*)d_in[10];
    const float* W_sig  = (const float*)d_in[11];
    const float* b_sig  = (const float*)d_in[12];
    const float* W_ih_d = (const float*)d_in[13];
    const float* b_ih_d = (const float*)d_in[14];
    const float* W_hh_d = (const float*)d_in[15];
    const float* b_hh_d = (const float*)d_in[16];
    const float* W_wr   = (const float*)d_in[17];
    const float* b_wr   = (const float*)d_in[18];
    float* out = (float*)d_out;

    float* f = (float*)d_ws;
    float* c_t   = f; f += 524288;
    float* base  = f; f += 524288;
    float* part  = f; f += (size_t)16 * 32 * 16384;   // 32 MB partials (max: enc)
    float* c_enc = f; f += 131072;
    float* c_dec = f; f += 131072;
    bf16* bp      = (bf16*)f;
    bf16* act_enc = bp; bp += (size_t)B_ * 6144;
    bf16* act_dec = bp; bp += (size_t)B_ * 1280;
    bf16* x_bf    = bp; bp += (size_t)B_ * 4096;
    bf16* Wenc    = bp; bp += (size_t)4096 * 6144;
    bf16* Wsum    = bp; bp += (size_t)4096 * 4096;
    bf16* Wdec    = bp; bp += (size_t)4096 * 1280;
    bf16* Wms     = bp; bp += (size_t)512 * 1024;
    bf16* Wwr     = bp; bp += (size_t)4096 * 1024;

    dim3 blk(256);

    init_k<<<(PBL + 255) / 256, blk, 0, stream>>>(x, c0, h0e, h0d, c_t, c_enc, c_dec,
                                                  act_enc, act_dec, x_bf);
    conv_enc_k<<<(4096 * 768 + 255) / 256, blk, 0, stream>>>(W_ih_e, W_hh_e, Wenc);
    conv_sum_k<<<(4096 * 512 + 255) / 256, blk, 0, stream>>>(W_ih_e, Wsum);
    conv_dec_k<<<(4096 * 160 + 255) / 256, blk, 0, stream>>>(W_ih_d, W_hh_d, Wdec);
    conv_ms_k<<<(512 * 128 + 255) / 256, blk, 0, stream>>>(W_mu, W_sig, Wms);
    conv_wr_k<<<(4096 * 128 + 255) / 256, blk, 0, stream>>>(W_wr, Wwr);

    // base = b_ih_e + b_hh_e + x @ Wsum^T  (gate-permuted), z=8, Kc=512
    gemm_k<<<dim3(32, 8), blk, 0, stream>>>(x_bf, 4096, Wsum, 4096, 512, part);
    fin_k<0, 8><<<dim3(32, 4), blk, 0, stream>>>(part, nullptr, base, nullptr, nullptr,
                                                 b_ih_e, b_hh_e, nullptr, nullptr);

    for (int t = 0; t < T_; ++t) {
        // encoder gates: [negs | h_dec | h_enc] @ Wenc^T, K=6144, z=16, Kc=384
        gemm_k<<<dim3(32, 16), blk, 0, stream>>>(act_enc, 6144, Wenc, 6144, 384, part);
        fin_k<1, 16><<<dim3(32, 4), blk, 0, stream>>>(part, base, c_enc, act_enc, nullptr,
                                                      nullptr, nullptr, nullptr, nullptr);
        // mu/sigma: h_enc @ Wms^T, N=512, K=1024, z=8, Kc=128
        gemm_k<<<dim3(4, 8), blk, 0, stream>>>(act_enc + 5120, 6144, Wms, 1024, 128, part);
        fin_k<2, 8><<<dim3(4, 4), blk, 0, stream>>>(part, nullptr, nullptr, nullptr, act_dec,
                                                    b_mu, b_sig, eps + (size_t)t * (B_ * 256),
                                                    nullptr);
        // decoder gates: [z | h_dec] @ Wdec^T, K=1280, z=5, Kc=256
        gemm_k<<<dim3(32, 5), blk, 0, stream>>>(act_dec, 1280, Wdec, 1280, 256, part);
        fin_k<3, 5><<<dim3(32, 4), blk, 0, stream>>>(part, nullptr, c_dec, act_enc, act_dec,
                                                     b_ih_d, b_hh_d, nullptr, nullptr);
        // write: c_t += h_dec @ Wwr^T + b_wr; negs (+ out at last step), z=8, Kc=128
        gemm_k<<<dim3(32, 8), blk, 0, stream>>>(act_dec + 256, 1280, Wwr, 1024, 128, part);
        fin_k<4, 8><<<dim3(32, 4), blk, 0, stream>>>(part, nullptr, c_t, act_enc, nullptr,
                                                     b_wr, nullptr, nullptr,
                                                     (t == T_ - 1) ? out : nullptr);
    }
}